// Round 21
// baseline (294.954 us; speedup 1.0000x reference)
//
#include <hip/hip_runtime.h>
#include <cstdint>
#include <cstddef>

typedef unsigned int u32;
typedef unsigned short u16;
typedef __bf16 bf16x8 __attribute__((ext_vector_type(8)));
typedef float f32x4 __attribute__((ext_vector_type(4)));
typedef u32 u32x4 __attribute__((ext_vector_type(4)));
typedef u16 u16x8 __attribute__((ext_vector_type(8)));

#define B_ 4
#define N_ 2048
#define C_ 1024
#define H_ 16
#define D_ 64

#if __has_builtin(__builtin_amdgcn_exp2f)
#define EXP2F __builtin_amdgcn_exp2f
#else
#define EXP2F exp2f
#endif

__device__ __forceinline__ u16 bf16rn(float f) {
  u32 u = __builtin_bit_cast(u32, f);
  return (u16)((u + 0x7FFFu + ((u >> 16) & 1u)) >> 16);
}
__device__ __forceinline__ float bf2f(u16 h) {
  u32 u = ((u32)h) << 16;
  return __builtin_bit_cast(float, u);
}
__device__ __forceinline__ u32 cvtpk_bf16(float lo, float hi) {
  u32 r;
  asm("v_cvt_pk_bf16_f32 %0, %1, %2" : "=v"(r) : "v"(lo), "v"(hi));
  return r;
}

__device__ __forceinline__ void gload16(const u16* g, u16* l) {
  __builtin_amdgcn_global_load_lds(
      (const __attribute__((address_space(1))) u32*)g,
      (__attribute__((address_space(3))) u32*)l, 16, 0, 0);
}

// ---------------- fused pack f32 -> bf16 (x, qkv_w, proj_w in one launch) ----------------
#define NX8 1048576   // 8192*1024/8
#define NW8 393216    // 3072*1024/8
#define NP8 131072    // 1024*1024/8
__global__ __launch_bounds__(256)
void pack_all(const float* __restrict__ x, const float* __restrict__ qw,
              const float* __restrict__ pw, u16* __restrict__ xb,
              u16* __restrict__ wb, u16* __restrict__ pwb) {
  int i = blockIdx.x * 256 + threadIdx.x;   // 0 .. NX8+NW8+NP8-1
  const float* src;
  u16* dst;
  int j;
  if (i < NX8) {
    src = x; dst = xb; j = i;
  } else if (i < NX8 + NW8) {
    src = qw; dst = wb; j = i - NX8;
  } else {
    src = pw; dst = pwb; j = i - (NX8 + NW8);
  }
  const float4* p4 = (const float4*)src + (size_t)j * 2;
  float4 a = p4[0], b = p4[1];
  u16x8 v;
  v[0] = bf16rn(a.x); v[1] = bf16rn(a.y); v[2] = bf16rn(a.z); v[3] = bf16rn(a.w);
  v[4] = bf16rn(b.x); v[5] = bf16rn(b.y); v[6] = bf16rn(b.z); v[7] = bf16rn(b.w);
  *((u16x8*)dst + j) = v;
}

// ---------------- bf16 GEMM, C = A * Bt^T — BK=64 + granule-XOR LDS ----------------
// r18/r20 structure (HW-passed; EPI==0 fuses bias+RMSNorm+RoPE for q/k).
// r21 delta: __launch_bounds__(256,5) — LDS allows exactly 5 blocks/CU
// (5 x 32KB = 160KB), VGPR 64 fits the 102/wave cap. Pure occupancy hint.
template <int EPI>
__global__ __launch_bounds__(256, 5)
void gemm_bt(const u16* __restrict__ A, const u16* __restrict__ Bt,
             int M, int Nd, int K, const float* __restrict__ bias,
             u16* __restrict__ qo, u16* __restrict__ ko, u16* __restrict__ vto,
             float* __restrict__ fo,
             const float* __restrict__ qnw, const float* __restrict__ knw,
             const float* __restrict__ cost, const float* __restrict__ sint) {
  __shared__ u16 As[128 * 64];
  __shared__ u16 Bs[128 * 64];
  const int tid = threadIdx.x;
  const int lane = tid & 63;
  const int wid = tid >> 6;
  const int wr = wid >> 1, wc = wid & 1;
  const int l15 = lane & 15, g = lane >> 4;
  const int nn = Nd >> 7;
  const int bsw = (blockIdx.x & 7) * ((int)gridDim.x >> 3) + (blockIdx.x >> 3);
  const int bn = bsw % nn, bm = bsw / nn;     // bn fastest: A-panel reuse
  const long m0 = (long)bm * 128, n0 = (long)bn * 128;
  const u16* Ag = A + m0 * K;
  const u16* Bg = Bt + n0 * K;
  f32x4 acc[4][4] = {};

  for (int kt = 0; kt < K; kt += 64) {
    __syncthreads();
#pragma unroll
    for (int i = 0; i < 4; i++) {
      const int gi = i * 256 + tid;            // granule 0..1023
      const int r = gi >> 3;                   // tile row 0..127
      const int c8 = ((gi & 7) ^ (r & 7)) * 8; // inverse-permuted source granule
      gload16(Ag + (long)r * K + kt + c8, As + (size_t)gi * 8);
      gload16(Bg + (long)r * K + kt + c8, Bs + (size_t)gi * 8);
    }
    __syncthreads();
    bf16x8 af[4][2], bfr[4][2];
#pragma unroll
    for (int i = 0; i < 4; i++) {
      const int ar = wr * 64 + i * 16 + l15;
      const int br = wc * 64 + i * 16 + l15;
#pragma unroll
      for (int kk = 0; kk < 2; kk++) {
        af[i][kk] = *(const bf16x8*)(As + ar * 64 + (((kk * 4 + g) ^ (ar & 7)) * 8));
        bfr[i][kk] = *(const bf16x8*)(Bs + br * 64 + (((kk * 4 + g) ^ (br & 7)) * 8));
      }
    }
#pragma unroll
    for (int kk = 0; kk < 2; kk++)
#pragma unroll
      for (int i = 0; i < 4; i++)
#pragma unroll
        for (int j = 0; j < 4; j++)
          acc[i][j] = __builtin_amdgcn_mfma_f32_16x16x32_bf16(af[i][kk], bfr[j][kk],
                                                              acc[i][j], 0, 0, 0);
  }

  if (EPI == 0) {
    const int o0 = (int)n0 + wc * 64;          // wave-uniform 64-col window base
    const int seg = o0 >> 10;                  // wave-uniform: 0=q 1=k 2=v
    const int h = (o0 & 1023) >> 6;            // wave-uniform head
    if (seg == 2) {
#pragma unroll
      for (int nj = 0; nj < 4; nj++) {
        const int o = o0 + nj * 16 + l15;
        const float bv = bias[o];
        const int d = o & 63;
#pragma unroll
        for (int mi = 0; mi < 4; mi++) {
          const int m = (int)m0 + wr * 64 + mi * 16 + g * 4;
          const int b = m >> 11, nt = m & 2047;
          const long vbase = (((long)(b * 16 + h)) * 64 + d) * 2048 + nt;
          u16 pk[4];
#pragma unroll
          for (int j = 0; j < 4; j++) pk[j] = bf16rn(acc[mi][nj][j] + bv);
          uint2 val;
          val.x = (u32)pk[0] | ((u32)pk[1] << 16);
          val.y = (u32)pk[2] | ((u32)pk[3] << 16);
          *(uint2*)(vto + vbase) = val;
        }
      }
    } else {
      const float qscale =
          (seg == 0) ? 0.125f * 1.44269504088896340736f : 1.0f;
      const float* nw = (seg == 0) ? qnw : knw;
      u16* outp = (seg == 0) ? qo : ko;
      float bvv[4], wv[4];
#pragma unroll
      for (int nj = 0; nj < 4; nj++) {
        bvv[nj] = bias[o0 + nj * 16 + l15];
        wv[nj] = nw[nj * 16 + l15];
      }
#pragma unroll
      for (int mi = 0; mi < 4; mi++) {
#pragma unroll
        for (int j = 0; j < 4; j++) {
          const int m = (int)m0 + wr * 64 + mi * 16 + g * 4 + j;
          const int b = m >> 11, n = m & 2047;
          const float v0 = acc[mi][0][j] + bvv[0];
          const float v1 = acc[mi][1][j] + bvv[1];
          const float v2 = acc[mi][2][j] + bvv[2];
          const float v3 = acc[mi][3][j] + bvv[3];
          float ss = v0 * v0 + v1 * v1 + v2 * v2 + v3 * v3;
          ss += __shfl_xor(ss, 1);
          ss += __shfl_xor(ss, 2);
          ss += __shfl_xor(ss, 4);
          ss += __shfl_xor(ss, 8);
          const float r = rsqrtf(ss * (1.0f / 64.0f) + 1e-6f);
          const float vn0 = v0 * r * wv[0];
          const float vn1 = v1 * r * wv[1];
          const float vn2 = v2 * r * wv[2];
          const float vn3 = v3 * r * wv[3];
          const float* cb = cost + n * 64 + l15;
          const float* sb = sint + n * 64 + l15;
          const float res0 = (vn0 * cb[0]  - vn2 * sb[0])  * qscale;
          const float res1 = (vn1 * cb[16] - vn3 * sb[16]) * qscale;
          const float res2 = (vn2 * cb[32] + vn0 * sb[32]) * qscale;
          const float res3 = (vn3 * cb[48] + vn1 * sb[48]) * qscale;
          u16* dst = outp + (((long)(b * 16 + h)) * 2048 + n) * 64 + l15;
          dst[0]  = bf16rn(res0);
          dst[16] = bf16rn(res1);
          dst[32] = bf16rn(res2);
          dst[48] = bf16rn(res3);
        }
      }
    }
  } else {
#pragma unroll
    for (int nj = 0; nj < 4; nj++) {
      const int o = (int)n0 + wc * 64 + nj * 16 + l15;
      const float bv = bias[o];
#pragma unroll
      for (int mi = 0; mi < 4; mi++) {
        const long m = m0 + wr * 64 + mi * 16 + g * 4;
#pragma unroll
        for (int j = 0; j < 4; j++) fo[(m + j) * (long)Nd + o] = acc[mi][nj][j] + bv;
      }
    }
  }
}

// ---------------- flash attention: r20-EXACT (HW-passed, 80.5µs) ----------------
#define FK(r) (((r) & 3) | ((((r) >> 3) & 1) << 2))

#define STAGE_KV(BUF, K0)                                                     \
  do {                                                                        \
    const int kr_ = tid >> 3;                                                 \
    const int kc8_ = ((tid & 7) ^ FK(kr_)) * 8;                               \
    gload16(Kp + (size_t)((K0) + kr_) * 64 + kc8_, Ks[BUF] + tid * 8);        \
    const int vr2_ = tid >> 2;                                                \
    const int vc8_ = ((tid & 3) ^ ((vr2_ >> 1) & 3)) * 8;                     \
    gload16(Vt + (size_t)vr2_ * 2048 + (K0) + vc8_, Vs[BUF] + tid * 8);       \
  } while (0)

#define LOADKV_LDS(KF, VF, BUF)                                               \
  do {                                                                        \
    KF[0] = *(const bf16x8*)(Ks[BUF] + s0r * 64 + ((g ^ fk0) * 8));           \
    KF[1] = *(const bf16x8*)(Ks[BUF] + s0r * 64 + (((4 + g) ^ fk0) * 8));     \
    KF[2] = *(const bf16x8*)(Ks[BUF] + s1r * 64 + ((g ^ fk1) * 8));           \
    KF[3] = *(const bf16x8*)(Ks[BUF] + s1r * 64 + (((4 + g) ^ fk1) * 8));     \
    _Pragma("unroll") for (int dc_ = 0; dc_ < 4; dc_++) {                     \
      const int vr_ = dc_ * 16 + l15;                                         \
      VF[dc_] = *(const bf16x8*)(Vs[BUF] + vr_ * 32 +                         \
                                 ((g ^ ((vr_ >> 1) & 3)) * 8));               \
    }                                                                         \
  } while (0)

#define ATTN_STEP(KF, VF)                                                     \
  do {                                                                        \
    _Pragma("unroll") for (int t = 0; t < 2; t++) {                           \
      f32x4 s0 = {}, s1 = {};                                                 \
      __builtin_amdgcn_s_setprio(1);                                          \
      s0 = __builtin_amdgcn_mfma_f32_16x16x32_bf16(KF[0], qf[t][0], s0, 0, 0, 0); \
      s0 = __builtin_amdgcn_mfma_f32_16x16x32_bf16(KF[1], qf[t][1], s0, 0, 0, 0); \
      s1 = __builtin_amdgcn_mfma_f32_16x16x32_bf16(KF[2], qf[t][0], s1, 0, 0, 0); \
      s1 = __builtin_amdgcn_mfma_f32_16x16x32_bf16(KF[3], qf[t][1], s1, 0, 0, 0); \
      __builtin_amdgcn_s_setprio(0);                                          \
      const float p0 = EXP2F(s0[0]), p1 = EXP2F(s0[1]);                       \
      const float p2 = EXP2F(s0[2]), p3 = EXP2F(s0[3]);                       \
      const float p4 = EXP2F(s1[0]), p5 = EXP2F(s1[1]);                       \
      const float p6 = EXP2F(s1[2]), p7 = EXP2F(s1[3]);                       \
      u32x4 pw;                                                               \
      pw[0] = cvtpk_bf16(p0, p1);                                             \
      pw[1] = cvtpk_bf16(p2, p3);                                             \
      pw[2] = cvtpk_bf16(p4, p5);                                             \
      pw[3] = cvtpk_bf16(p6, p7);                                             \
      const bf16x8 pb = __builtin_bit_cast(bf16x8, pw);                       \
      __builtin_amdgcn_s_setprio(1);                                          \
      lacc[t] = __builtin_amdgcn_mfma_f32_16x16x32_bf16(onesv, pb, lacc[t], 0, 0, 0); \
      _Pragma("unroll") for (int dc = 0; dc < 4; dc++)                        \
          oacc[t][dc] = __builtin_amdgcn_mfma_f32_16x16x32_bf16(              \
              VF[dc], pb, oacc[t][dc], 0, 0, 0);                              \
      __builtin_amdgcn_s_setprio(0);                                          \
    }                                                                         \
  } while (0)

__global__ __launch_bounds__(256, 4)
void attn_fwd(const u16* __restrict__ qb, const u16* __restrict__ kb,
              const u16* __restrict__ vt, u16* __restrict__ ob) {
  __shared__ __align__(16) u16 Ks[2][32 * 64];  // [buf][key 0..31][D], r11 geometry
  __shared__ __align__(16) u16 Vs[2][64 * 32];  // [buf][d 0..63][key 0..31], r11 geometry
  const int tid = threadIdx.x;
  const int lane = tid & 63;
  const int l15 = lane & 15, g = lane >> 4;
  const int wid = tid >> 6;                     // 0..3
  const int bid = blockIdx.x;
  // 1024 blocks over 8 XCDs; 8 bh per XCD -> K/V working set ~4MB = one L2.
  const int xcd = bid & 7, idx = bid >> 3;      // idx 0..127  (r8-proven map)
  const int bh = xcd * 8 + (idx >> 4);
  const int q0 = (idx & 15) * 128 + wid * 32;   // 4 waves x 32 q-rows
  const u16* Q = qb + (size_t)bh * (N_ * D_);
  const u16* Kp = kb + (size_t)bh * (N_ * D_);
  const u16* Vt = vt + (size_t)bh * (D_ * N_);

  bf16x8 qf[2][2];
#pragma unroll
  for (int t = 0; t < 2; t++) {
    qf[t][0] = *(const bf16x8*)(Q + (size_t)(q0 + t * 16 + l15) * 64 + g * 8);
    qf[t][1] = *(const bf16x8*)(Q + (size_t)(q0 + t * 16 + l15) * 64 + 32 + g * 8);
  }
  f32x4 oacc[2][4] = {};
  f32x4 lacc[2] = {};

  // all-ones bf16 A-operand for the l-sum MFMA (r8/r11-proven)
  const u32x4 onesw = {0x3F803F80u, 0x3F803F80u, 0x3F803F80u, 0x3F803F80u};
  const bf16x8 onesv = __builtin_bit_cast(bf16x8, onesw);

  // sigma-permuted K fragment rows + their granule-XOR keys
  const int s0r = (l15 >> 2) * 8 + (l15 & 3);
  const int s1r = s0r + 4;
  const int fk0 = FK(s0r), fk1 = FK(s1r);

  bf16x8 kf[4], vf[4];
  int cur = 0;
  STAGE_KV(0, 0);
  __syncthreads();
  for (int k0 = 0; k0 < N_; k0 += 32) {
    if (k0 + 32 < N_) STAGE_KV(cur ^ 1, k0 + 32);
    LOADKV_LDS(kf, vf, cur);
    ATTN_STEP(kf, vf);
    __syncthreads();  // drains this step's stage vmcnt + read lgkm
    cur ^= 1;
  }

  const int b = bh >> 4, h = bh & 15;
#pragma unroll
  for (int t = 0; t < 2; t++) {
    const float inv = 1.0f / lacc[t][0];
    const size_t mm = (size_t)b * 2048 + q0 + t * 16 + l15;
    u16* orow = ob + mm * 1024 + h * 64;
#pragma unroll
    for (int dc = 0; dc < 4; dc++) {
      uint2 val;
      val.x = cvtpk_bf16(oacc[t][dc][0] * inv, oacc[t][dc][1] * inv);
      val.y = cvtpk_bf16(oacc[t][dc][2] * inv, oacc[t][dc][3] * inv);
      *(uint2*)(orow + dc * 16 + g * 4) = val;
    }
  }
}

// ---------------- host launch ----------------
extern "C" void kernel_launch(void* const* d_in, const int* in_sizes, int n_in,
                              void* d_out, int out_size, void* d_ws, size_t ws_size,
                              hipStream_t stream) {
  (void)in_sizes; (void)n_in; (void)out_size; (void)ws_size;
  const float* x = (const float*)d_in[0];
  const float* qkvw = (const float*)d_in[1];
  const float* qkvb = (const float*)d_in[2];
  const float* projw = (const float*)d_in[3];
  const float* projb = (const float*)d_in[4];
  const float* qnw = (const float*)d_in[5];
  const float* knw = (const float*)d_in[6];
  const float* cost = (const float*)d_in[7];
  const float* sint = (const float*)d_in[8];
  float* out = (float*)d_out;

  char* ws = (char*)d_ws;
  u16* xb = (u16*)ws;        ws += (size_t)8192 * 1024 * 2;
  u16* wb = (u16*)ws;        ws += (size_t)3072 * 1024 * 2;
  u16* pwb = (u16*)ws;       ws += (size_t)1024 * 1024 * 2;
  u16* qraw = (u16*)ws;      ws += (size_t)8192 * 1024 * 2;
  u16* kraw = (u16*)ws;      ws += (size_t)8192 * 1024 * 2;
  u16* vt = (u16*)ws;        ws += (size_t)8192 * 1024 * 2;
  u16* ob = (u16*)ws;        ws += (size_t)8192 * 1024 * 2;

  pack_all<<<dim3((NX8 + NW8 + NP8) / 256), dim3(256), 0, stream>>>(
      x, qkvw, projw, xb, wb, pwb);

  gemm_bt<0><<<dim3(64 * 24), dim3(256), 0, stream>>>(
      xb, wb, 8192, 3072, 1024, qkvb, qraw, kraw, vt, nullptr,
      qnw, knw, cost, sint);
  attn_fwd<<<dim3(1024), dim3(256), 0, stream>>>(qraw, kraw, vt, ob);
  gemm_bt<1><<<dim3(64 * 8), dim3(256), 0, stream>>>(
      ob, pwb, 8192, 1024, 1024, projb, nullptr, nullptr, nullptr, out,
      nullptr, nullptr, nullptr, nullptr);
}

// Round 22
// 177.023 us; speedup vs baseline: 1.6662x; 1.6662x over previous
//
#include <hip/hip_runtime.h>
#include <cstdint>
#include <cstddef>

typedef unsigned int u32;
typedef unsigned short u16;
typedef __bf16 bf16x8 __attribute__((ext_vector_type(8)));
typedef float f32x4 __attribute__((ext_vector_type(4)));
typedef u32 u32x4 __attribute__((ext_vector_type(4)));
typedef u16 u16x8 __attribute__((ext_vector_type(8)));

#define B_ 4
#define N_ 2048
#define C_ 1024
#define H_ 16
#define D_ 64

#if __has_builtin(__builtin_amdgcn_exp2f)
#define EXP2F __builtin_amdgcn_exp2f
#else
#define EXP2F exp2f
#endif

__device__ __forceinline__ u16 bf16rn(float f) {
  u32 u = __builtin_bit_cast(u32, f);
  return (u16)((u + 0x7FFFu + ((u >> 16) & 1u)) >> 16);
}
__device__ __forceinline__ float bf2f(u16 h) {
  u32 u = ((u32)h) << 16;
  return __builtin_bit_cast(float, u);
}
__device__ __forceinline__ u32 cvtpk_bf16(float lo, float hi) {
  u32 r;
  asm("v_cvt_pk_bf16_f32 %0, %1, %2" : "=v"(r) : "v"(lo), "v"(hi));
  return r;
}

__device__ __forceinline__ void gload16(const u16* g, u16* l) {
  __builtin_amdgcn_global_load_lds(
      (const __attribute__((address_space(1))) u32*)g,
      (__attribute__((address_space(3))) u32*)l, 16, 0, 0);
}

// ---------------- fused pack f32 -> bf16 (x, qkv_w, proj_w in one launch) ----------------
#define NX8 1048576   // 8192*1024/8
#define NW8 393216    // 3072*1024/8
#define NP8 131072    // 1024*1024/8
__global__ __launch_bounds__(256)
void pack_all(const float* __restrict__ x, const float* __restrict__ qw,
              const float* __restrict__ pw, u16* __restrict__ xb,
              u16* __restrict__ wb, u16* __restrict__ pwb) {
  int i = blockIdx.x * 256 + threadIdx.x;   // 0 .. NX8+NW8+NP8-1
  const float* src;
  u16* dst;
  int j;
  if (i < NX8) {
    src = x; dst = xb; j = i;
  } else if (i < NX8 + NW8) {
    src = qw; dst = wb; j = i - NX8;
  } else {
    src = pw; dst = pwb; j = i - (NX8 + NW8);
  }
  const float4* p4 = (const float4*)src + (size_t)j * 2;
  float4 a = p4[0], b = p4[1];
  u16x8 v;
  v[0] = bf16rn(a.x); v[1] = bf16rn(a.y); v[2] = bf16rn(a.z); v[3] = bf16rn(a.w);
  v[4] = bf16rn(b.x); v[5] = bf16rn(b.y); v[6] = bf16rn(b.z); v[7] = bf16rn(b.w);
  *((u16x8*)dst + j) = v;
}

// ---------------- bf16 GEMM, C = A * Bt^T — BK=64 + granule-XOR LDS ----------------
// r20-EXACT (HW-passed): __launch_bounds__(256,4). r21's (256,5) forced the
// allocator to 48 VGPR -> acc[4][4] spilled to scratch (109MB write stream,
// MfmaUtil 11%) — 4 blocks/CU is the VGPR-feasible max for this kernel.
template <int EPI>
__global__ __launch_bounds__(256, 4)
void gemm_bt(const u16* __restrict__ A, const u16* __restrict__ Bt,
             int M, int Nd, int K, const float* __restrict__ bias,
             u16* __restrict__ qo, u16* __restrict__ ko, u16* __restrict__ vto,
             float* __restrict__ fo,
             const float* __restrict__ qnw, const float* __restrict__ knw,
             const float* __restrict__ cost, const float* __restrict__ sint) {
  __shared__ u16 As[128 * 64];
  __shared__ u16 Bs[128 * 64];
  const int tid = threadIdx.x;
  const int lane = tid & 63;
  const int wid = tid >> 6;
  const int wr = wid >> 1, wc = wid & 1;
  const int l15 = lane & 15, g = lane >> 4;
  const int nn = Nd >> 7;
  const int bsw = (blockIdx.x & 7) * ((int)gridDim.x >> 3) + (blockIdx.x >> 3);
  const int bn = bsw % nn, bm = bsw / nn;     // bn fastest: A-panel reuse
  const long m0 = (long)bm * 128, n0 = (long)bn * 128;
  const u16* Ag = A + m0 * K;
  const u16* Bg = Bt + n0 * K;
  f32x4 acc[4][4] = {};

  for (int kt = 0; kt < K; kt += 64) {
    __syncthreads();
#pragma unroll
    for (int i = 0; i < 4; i++) {
      const int gi = i * 256 + tid;            // granule 0..1023
      const int r = gi >> 3;                   // tile row 0..127
      const int c8 = ((gi & 7) ^ (r & 7)) * 8; // inverse-permuted source granule
      gload16(Ag + (long)r * K + kt + c8, As + (size_t)gi * 8);
      gload16(Bg + (long)r * K + kt + c8, Bs + (size_t)gi * 8);
    }
    __syncthreads();
    bf16x8 af[4][2], bfr[4][2];
#pragma unroll
    for (int i = 0; i < 4; i++) {
      const int ar = wr * 64 + i * 16 + l15;
      const int br = wc * 64 + i * 16 + l15;
#pragma unroll
      for (int kk = 0; kk < 2; kk++) {
        af[i][kk] = *(const bf16x8*)(As + ar * 64 + (((kk * 4 + g) ^ (ar & 7)) * 8));
        bfr[i][kk] = *(const bf16x8*)(Bs + br * 64 + (((kk * 4 + g) ^ (br & 7)) * 8));
      }
    }
#pragma unroll
    for (int kk = 0; kk < 2; kk++)
#pragma unroll
      for (int i = 0; i < 4; i++)
#pragma unroll
        for (int j = 0; j < 4; j++)
          acc[i][j] = __builtin_amdgcn_mfma_f32_16x16x32_bf16(af[i][kk], bfr[j][kk],
                                                              acc[i][j], 0, 0, 0);
  }

  if (EPI == 0) {
    const int o0 = (int)n0 + wc * 64;          // wave-uniform 64-col window base
    const int seg = o0 >> 10;                  // wave-uniform: 0=q 1=k 2=v
    const int h = (o0 & 1023) >> 6;            // wave-uniform head
    if (seg == 2) {
#pragma unroll
      for (int nj = 0; nj < 4; nj++) {
        const int o = o0 + nj * 16 + l15;
        const float bv = bias[o];
        const int d = o & 63;
#pragma unroll
        for (int mi = 0; mi < 4; mi++) {
          const int m = (int)m0 + wr * 64 + mi * 16 + g * 4;
          const int b = m >> 11, nt = m & 2047;
          const long vbase = (((long)(b * 16 + h)) * 64 + d) * 2048 + nt;
          u16 pk[4];
#pragma unroll
          for (int j = 0; j < 4; j++) pk[j] = bf16rn(acc[mi][nj][j] + bv);
          uint2 val;
          val.x = (u32)pk[0] | ((u32)pk[1] << 16);
          val.y = (u32)pk[2] | ((u32)pk[3] << 16);
          *(uint2*)(vto + vbase) = val;
        }
      }
    } else {
      const float qscale =
          (seg == 0) ? 0.125f * 1.44269504088896340736f : 1.0f;
      const float* nw = (seg == 0) ? qnw : knw;
      u16* outp = (seg == 0) ? qo : ko;
      float bvv[4], wv[4];
#pragma unroll
      for (int nj = 0; nj < 4; nj++) {
        bvv[nj] = bias[o0 + nj * 16 + l15];
        wv[nj] = nw[nj * 16 + l15];
      }
#pragma unroll
      for (int mi = 0; mi < 4; mi++) {
#pragma unroll
        for (int j = 0; j < 4; j++) {
          const int m = (int)m0 + wr * 64 + mi * 16 + g * 4 + j;
          const int b = m >> 11, n = m & 2047;
          const float v0 = acc[mi][0][j] + bvv[0];
          const float v1 = acc[mi][1][j] + bvv[1];
          const float v2 = acc[mi][2][j] + bvv[2];
          const float v3 = acc[mi][3][j] + bvv[3];
          float ss = v0 * v0 + v1 * v1 + v2 * v2 + v3 * v3;
          ss += __shfl_xor(ss, 1);
          ss += __shfl_xor(ss, 2);
          ss += __shfl_xor(ss, 4);
          ss += __shfl_xor(ss, 8);
          const float r = rsqrtf(ss * (1.0f / 64.0f) + 1e-6f);
          const float vn0 = v0 * r * wv[0];
          const float vn1 = v1 * r * wv[1];
          const float vn2 = v2 * r * wv[2];
          const float vn3 = v3 * r * wv[3];
          const float* cb = cost + n * 64 + l15;
          const float* sb = sint + n * 64 + l15;
          const float res0 = (vn0 * cb[0]  - vn2 * sb[0])  * qscale;
          const float res1 = (vn1 * cb[16] - vn3 * sb[16]) * qscale;
          const float res2 = (vn2 * cb[32] + vn0 * sb[32]) * qscale;
          const float res3 = (vn3 * cb[48] + vn1 * sb[48]) * qscale;
          u16* dst = outp + (((long)(b * 16 + h)) * 2048 + n) * 64 + l15;
          dst[0]  = bf16rn(res0);
          dst[16] = bf16rn(res1);
          dst[32] = bf16rn(res2);
          dst[48] = bf16rn(res3);
        }
      }
    }
  } else {
#pragma unroll
    for (int nj = 0; nj < 4; nj++) {
      const int o = (int)n0 + wc * 64 + nj * 16 + l15;
      const float bv = bias[o];
#pragma unroll
      for (int mi = 0; mi < 4; mi++) {
        const long m = m0 + wr * 64 + mi * 16 + g * 4;
#pragma unroll
        for (int j = 0; j < 4; j++) fo[(m + j) * (long)Nd + o] = acc[mi][nj][j] + bv;
      }
    }
  }
}

// ---------------- flash attention: r20-EXACT (HW-passed, 80.5µs) ----------------
#define FK(r) (((r) & 3) | ((((r) >> 3) & 1) << 2))

#define STAGE_KV(BUF, K0)                                                     \
  do {                                                                        \
    const int kr_ = tid >> 3;                                                 \
    const int kc8_ = ((tid & 7) ^ FK(kr_)) * 8;                               \
    gload16(Kp + (size_t)((K0) + kr_) * 64 + kc8_, Ks[BUF] + tid * 8);        \
    const int vr2_ = tid >> 2;                                                \
    const int vc8_ = ((tid & 3) ^ ((vr2_ >> 1) & 3)) * 8;                     \
    gload16(Vt + (size_t)vr2_ * 2048 + (K0) + vc8_, Vs[BUF] + tid * 8);       \
  } while (0)

#define LOADKV_LDS(KF, VF, BUF)                                               \
  do {                                                                        \
    KF[0] = *(const bf16x8*)(Ks[BUF] + s0r * 64 + ((g ^ fk0) * 8));           \
    KF[1] = *(const bf16x8*)(Ks[BUF] + s0r * 64 + (((4 + g) ^ fk0) * 8));     \
    KF[2] = *(const bf16x8*)(Ks[BUF] + s1r * 64 + ((g ^ fk1) * 8));           \
    KF[3] = *(const bf16x8*)(Ks[BUF] + s1r * 64 + (((4 + g) ^ fk1) * 8));     \
    _Pragma("unroll") for (int dc_ = 0; dc_ < 4; dc_++) {                     \
      const int vr_ = dc_ * 16 + l15;                                         \
      VF[dc_] = *(const bf16x8*)(Vs[BUF] + vr_ * 32 +                         \
                                 ((g ^ ((vr_ >> 1) & 3)) * 8));               \
    }                                                                         \
  } while (0)

#define ATTN_STEP(KF, VF)                                                     \
  do {                                                                        \
    _Pragma("unroll") for (int t = 0; t < 2; t++) {                           \
      f32x4 s0 = {}, s1 = {};                                                 \
      __builtin_amdgcn_s_setprio(1);                                          \
      s0 = __builtin_amdgcn_mfma_f32_16x16x32_bf16(KF[0], qf[t][0], s0, 0, 0, 0); \
      s0 = __builtin_amdgcn_mfma_f32_16x16x32_bf16(KF[1], qf[t][1], s0, 0, 0, 0); \
      s1 = __builtin_amdgcn_mfma_f32_16x16x32_bf16(KF[2], qf[t][0], s1, 0, 0, 0); \
      s1 = __builtin_amdgcn_mfma_f32_16x16x32_bf16(KF[3], qf[t][1], s1, 0, 0, 0); \
      __builtin_amdgcn_s_setprio(0);                                          \
      const float p0 = EXP2F(s0[0]), p1 = EXP2F(s0[1]);                       \
      const float p2 = EXP2F(s0[2]), p3 = EXP2F(s0[3]);                       \
      const float p4 = EXP2F(s1[0]), p5 = EXP2F(s1[1]);                       \
      const float p6 = EXP2F(s1[2]), p7 = EXP2F(s1[3]);                       \
      u32x4 pw;                                                               \
      pw[0] = cvtpk_bf16(p0, p1);                                             \
      pw[1] = cvtpk_bf16(p2, p3);                                             \
      pw[2] = cvtpk_bf16(p4, p5);                                             \
      pw[3] = cvtpk_bf16(p6, p7);                                             \
      const bf16x8 pb = __builtin_bit_cast(bf16x8, pw);                       \
      __builtin_amdgcn_s_setprio(1);                                          \
      lacc[t] = __builtin_amdgcn_mfma_f32_16x16x32_bf16(onesv, pb, lacc[t], 0, 0, 0); \
      _Pragma("unroll") for (int dc = 0; dc < 4; dc++)                        \
          oacc[t][dc] = __builtin_amdgcn_mfma_f32_16x16x32_bf16(              \
              VF[dc], pb, oacc[t][dc], 0, 0, 0);                              \
      __builtin_amdgcn_s_setprio(0);                                          \
    }                                                                         \
  } while (0)

__global__ __launch_bounds__(256, 4)
void attn_fwd(const u16* __restrict__ qb, const u16* __restrict__ kb,
              const u16* __restrict__ vt, u16* __restrict__ ob) {
  __shared__ __align__(16) u16 Ks[2][32 * 64];  // [buf][key 0..31][D], r11 geometry
  __shared__ __align__(16) u16 Vs[2][64 * 32];  // [buf][d 0..63][key 0..31], r11 geometry
  const int tid = threadIdx.x;
  const int lane = tid & 63;
  const int l15 = lane & 15, g = lane >> 4;
  const int wid = tid >> 6;                     // 0..3
  const int bid = blockIdx.x;
  // 1024 blocks over 8 XCDs; 8 bh per XCD -> K/V working set ~4MB = one L2.
  const int xcd = bid & 7, idx = bid >> 3;      // idx 0..127  (r8-proven map)
  const int bh = xcd * 8 + (idx >> 4);
  const int q0 = (idx & 15) * 128 + wid * 32;   // 4 waves x 32 q-rows
  const u16* Q = qb + (size_t)bh * (N_ * D_);
  const u16* Kp = kb + (size_t)bh * (N_ * D_);
  const u16* Vt = vt + (size_t)bh * (D_ * N_);

  bf16x8 qf[2][2];
#pragma unroll
  for (int t = 0; t < 2; t++) {
    qf[t][0] = *(const bf16x8*)(Q + (size_t)(q0 + t * 16 + l15) * 64 + g * 8);
    qf[t][1] = *(const bf16x8*)(Q + (size_t)(q0 + t * 16 + l15) * 64 + 32 + g * 8);
  }
  f32x4 oacc[2][4] = {};
  f32x4 lacc[2] = {};

  // all-ones bf16 A-operand for the l-sum MFMA (r8/r11-proven)
  const u32x4 onesw = {0x3F803F80u, 0x3F803F80u, 0x3F803F80u, 0x3F803F80u};
  const bf16x8 onesv = __builtin_bit_cast(bf16x8, onesw);

  // sigma-permuted K fragment rows + their granule-XOR keys
  const int s0r = (l15 >> 2) * 8 + (l15 & 3);
  const int s1r = s0r + 4;
  const int fk0 = FK(s0r), fk1 = FK(s1r);

  bf16x8 kf[4], vf[4];
  int cur = 0;
  STAGE_KV(0, 0);
  __syncthreads();
  for (int k0 = 0; k0 < N_; k0 += 32) {
    if (k0 + 32 < N_) STAGE_KV(cur ^ 1, k0 + 32);
    LOADKV_LDS(kf, vf, cur);
    ATTN_STEP(kf, vf);
    __syncthreads();  // drains this step's stage vmcnt + read lgkm
    cur ^= 1;
  }

  const int b = bh >> 4, h = bh & 15;
#pragma unroll
  for (int t = 0; t < 2; t++) {
    const float inv = 1.0f / lacc[t][0];
    const size_t mm = (size_t)b * 2048 + q0 + t * 16 + l15;
    u16* orow = ob + mm * 1024 + h * 64;
#pragma unroll
    for (int dc = 0; dc < 4; dc++) {
      uint2 val;
      val.x = cvtpk_bf16(oacc[t][dc][0] * inv, oacc[t][dc][1] * inv);
      val.y = cvtpk_bf16(oacc[t][dc][2] * inv, oacc[t][dc][3] * inv);
      *(uint2*)(orow + dc * 16 + g * 4) = val;
    }
  }
}

// ---------------- host launch ----------------
extern "C" void kernel_launch(void* const* d_in, const int* in_sizes, int n_in,
                              void* d_out, int out_size, void* d_ws, size_t ws_size,
                              hipStream_t stream) {
  (void)in_sizes; (void)n_in; (void)out_size; (void)ws_size;
  const float* x = (const float*)d_in[0];
  const float* qkvw = (const float*)d_in[1];
  const float* qkvb = (const float*)d_in[2];
  const float* projw = (const float*)d_in[3];
  const float* projb = (const float*)d_in[4];
  const float* qnw = (const float*)d_in[5];
  const float* knw = (const float*)d_in[6];
  const float* cost = (const float*)d_in[7];
  const float* sint = (const float*)d_in[8];
  float* out = (float*)d_out;

  char* ws = (char*)d_ws;
  u16* xb = (u16*)ws;        ws += (size_t)8192 * 1024 * 2;
  u16* wb = (u16*)ws;        ws += (size_t)3072 * 1024 * 2;
  u16* pwb = (u16*)ws;       ws += (size_t)1024 * 1024 * 2;
  u16* qraw = (u16*)ws;      ws += (size_t)8192 * 1024 * 2;
  u16* kraw = (u16*)ws;      ws += (size_t)8192 * 1024 * 2;
  u16* vt = (u16*)ws;        ws += (size_t)8192 * 1024 * 2;
  u16* ob = (u16*)ws;        ws += (size_t)8192 * 1024 * 2;

  pack_all<<<dim3((NX8 + NW8 + NP8) / 256), dim3(256), 0, stream>>>(
      x, qkvw, projw, xb, wb, pwb);

  gemm_bt<0><<<dim3(64 * 24), dim3(256), 0, stream>>>(
      xb, wb, 8192, 3072, 1024, qkvb, qraw, kraw, vt, nullptr,
      qnw, knw, cost, sint);
  attn_fwd<<<dim3(1024), dim3(256), 0, stream>>>(qraw, kraw, vt, ob);
  gemm_bt<1><<<dim3(64 * 8), dim3(256), 0, stream>>>(
      ob, pwb, 8192, 1024, 1024, projb, nullptr, nullptr, nullptr, out,
      nullptr, nullptr, nullptr, nullptr);
}